// Round 5
// baseline (394.384 us; speedup 1.0000x reference)
//
#include <hip/hip_runtime.h>

#define EN 2048
#define NCH 256
#define CTH 1024
#define SENT 0xFFFFFFFFu

// ws float offsets
#define T_OFF    0                  // 64 rows (sentinel-polled rows 1..63; row0 = x0, ATOMIC store)
#define H_OFF    (64 * EN)          // 64 rows (sentinel-polled rows 1..63); reused as RT1 after chain
#define FLG_OFF  (128 * EN)         // 6*256 done-flags (u32) in 1*EN floats
#define HT_OFF   (129 * EN)         // 127 rows -> ends at 256*EN
#define P_OFF    (256 * EN)         // 8 slots x 64 rows -> ends at 768*EN (6.3 MB total)

#define AL64(p)   __hip_atomic_load((const unsigned long long*)(p), __ATOMIC_RELAXED, __HIP_MEMORY_SCOPE_AGENT)
#define AL32(p)   __hip_atomic_load((const unsigned*)(p), __ATOMIC_RELAXED, __HIP_MEMORY_SCOPE_AGENT)
#define AS32(p,v) __hip_atomic_store((unsigned*)(p), (v), __ATOMIC_RELAXED, __HIP_MEMORY_SCOPE_AGENT)
#define AS64(p,v) __hip_atomic_store((unsigned long long*)(p), (v), __ATOMIC_RELAXED, __HIP_MEMORY_SCOPE_AGENT)

__device__ __forceinline__ float af(unsigned u) { return __uint_as_float(u); }

// fence-free all-blocks-done barrier: each wave's sc1 stores are drained by the
// compiler's vmcnt(0) before s_barrier; wave0 then sets this block's flag and
// polls all 256 flags (sc1 loads).
__device__ __forceinline__ void done_bar(unsigned* D, int b, int tid) {
    __syncthreads();
    if (tid < 64) {
        if (tid == 0) {
            asm volatile("s_waitcnt vmcnt(0)" ::: "memory");
            AS32(&D[b], 1u);
        }
        const unsigned long long* f = (const unsigned long long*)D;
        const unsigned long long GOOD = 0x0000000100000001ULL;
        for (long it = 0; it < 200000000L; ++it) {
            unsigned long long a = AL64(&f[tid * 2]);
            unsigned long long c = AL64(&f[tid * 2 + 1]);
            if (!__any((int)(a != GOOD || c != GOOD))) break;
        }
    }
    __syncthreads();
}

// 64x64 f32 partial GEMM tile: Pslot[0:64][c0:+64] = A[0:64][k0:+32*nch] @ W[..][c0:+64]
// A read via sc1 atomics (cross-XCD intra-kernel data), W plain (read-only input).
__device__ __forceinline__ void gemm64(
    const float* __restrict__ arow_thread, const float* __restrict__ Wmat,
    int k0base, int c0, float* __restrict__ Pslot, int nch, int tid,
    float (*As)[74], float (*Ws)[74])
{
    const int am   = tid >> 4;          // A row 0..63
    const int am_k = (tid & 15) * 2;    // A k-offset (float2)
    const int wk   = tid >> 5;          // W k-row 0..31
    const int wq2  = (tid & 31) * 2;    // W col pair
    const int tr2  = tid >> 5, tc2 = tid & 31;
    float acc00 = 0.f, acc01 = 0.f, acc10 = 0.f, acc11 = 0.f;

    unsigned long long ra = AL64(arow_thread + k0base + am_k);
    float2 rw = *(const float2*)(Wmat + (size_t)(k0base + wk) * EN + c0 + wq2);

    for (int kt = 0; kt < nch; ++kt) {
        __syncthreads();
        As[am_k][am]     = af((unsigned)ra);
        As[am_k + 1][am] = af((unsigned)(ra >> 32));
        Ws[wk][wq2]      = rw.x;
        Ws[wk][wq2 + 1]  = rw.y;
        __syncthreads();
        if (kt + 1 < nch) {
            int k0 = k0base + (kt + 1) * 32;
            ra = AL64(arow_thread + k0 + am_k);
            rw = *(const float2*)(Wmat + (size_t)(k0 + wk) * EN + c0 + wq2);
        }
#pragma unroll
        for (int kk = 0; kk < 32; ++kk) {
            float2 a  = *(const float2*)&As[kk][tr2 * 2];
            float2 w2 = *(const float2*)&Ws[kk][tc2 * 2];
            acc00 += a.x * w2.x; acc01 += a.x * w2.y;
            acc10 += a.y * w2.x; acc11 += a.y * w2.y;
        }
    }
    unsigned long long p0 = ((unsigned long long)__float_as_uint(acc01) << 32) | __float_as_uint(acc00);
    unsigned long long p1 = ((unsigned long long)__float_as_uint(acc11) << 32) | __float_as_uint(acc10);
    AS64(Pslot + (size_t)(tr2 * 2) * EN + c0 + tc2 * 2, p0);
    AS64(Pslot + (size_t)(tr2 * 2 + 1) * EN + c0 + tc2 * 2, p1);
}

__global__ __launch_bounds__(CTH, 1) void mega_kernel(
    const float* __restrict__ x0,
    const float* __restrict__ ul1W, const float* __restrict__ ul1b,
    const float* __restrict__ ul2W, const float* __restrict__ ul2b,
    const float* __restrict__ ur1W, const float* __restrict__ ur1b,
    const float* __restrict__ ur2W, const float* __restrict__ ur2b,
    const float* __restrict__ arW,  const float* __restrict__ arb,
    const float* __restrict__ aW,   const float* __restrict__ ab,
    float* __restrict__ T, float* __restrict__ Hb, float* __restrict__ RT1,
    float* __restrict__ HT, float* __restrict__ P, unsigned* __restrict__ FLG,
    float* __restrict__ out)
{
    __shared__ __align__(16) float xs[EN];
    __shared__ __align__(16) float red_t[16][20];
    __shared__ float bias_s[16];
    __shared__ float As[32][74];
    __shared__ float Ws[32][74];
    __shared__ float lred[16][2];

    const int tid  = threadIdx.x;
    const int b    = blockIdx.x;
    const int lane = tid & 63;
    const int wv   = tid >> 6;

    // ================= chain: 63 steps x 2 res-layers, pure dataflow =================
    {
        const int half  = b >> 7;         // 0 -> ul1 (produce H), 1 -> ul2 (produce T)
        const int idx   = b & 127;
        const int c0    = idx * 16;
        const int col   = tid & 15;
        const int chunk = tid >> 4;       // 0..63
        const float* Wg = half ? ul2W : ul1W;
        const float* bg = half ? ul2b : ul1b;

        float4 w[8];
#pragma unroll
        for (int j = 0; j < 8; ++j) {
            const float* wp = Wg + (size_t)(chunk * 32 + j * 4) * EN + c0 + col;
            w[j].x = wp[0]; w[j].y = wp[EN]; w[j].z = wp[2 * EN]; w[j].w = wp[3 * EN];
        }
        if (tid < 16) bias_s[tid] = bg[c0 + tid];

        for (int k = 1; k <= 63; ++k) {
            if (half == 0 && k == 1) {
                reinterpret_cast<float2*>(xs)[tid] = reinterpret_cast<const float2*>(x0)[tid];
            } else {
                const float* src = half ? (Hb + (size_t)k * EN) : (T + (size_t)(k - 1) * EN);
                const unsigned long long* s64 =
                    reinterpret_cast<const unsigned long long*>(src) + (size_t)wv * 64 + lane;
                unsigned long long v0 = AL64(s64), v1 = AL64(s64), vv;
                for (long it = 0;; ++it) {
                    { unsigned lo = (unsigned)v0, hi = (unsigned)(v0 >> 32);
                      if (!__any((int)(lo == SENT || hi == SENT))) { vv = v0; break; } }
                    v0 = AL64(s64);
                    { unsigned lo = (unsigned)v1, hi = (unsigned)(v1 >> 32);
                      if (!__any((int)(lo == SENT || hi == SENT))) { vv = v1; break; } }
                    v1 = AL64(s64);
                    if (it > 100000000L) { vv = v0; break; }
                }
                float2 xv;
                xv.x = af((unsigned)vv); xv.y = af((unsigned)(vv >> 32));
                reinterpret_cast<float2*>(xs)[tid] = xv;
            }
            __syncthreads();

            float s = 0.f;
            const float4* xv4 = reinterpret_cast<const float4*>(xs) + chunk * 8;
#pragma unroll
            for (int j = 0; j < 8; ++j) {
                float4 x4 = xv4[j];
                s += x4.x * w[j].x + x4.y * w[j].y + x4.z * w[j].z + x4.w * w[j].w;
            }
            s += __shfl_xor(s, 16, 64);
            s += __shfl_xor(s, 32, 64);
            if (lane < 16) red_t[lane][wv] = s;
            __syncthreads();

            if (wv == 0 && lane < 16) {
                float4 r0 = *(const float4*)&red_t[lane][0];
                float4 r1 = *(const float4*)&red_t[lane][4];
                float4 r2 = *(const float4*)&red_t[lane][8];
                float4 r3 = *(const float4*)&red_t[lane][12];
                float tot = ((r0.x + r0.y) + (r0.z + r0.w)) + ((r1.x + r1.y) + (r1.z + r1.w))
                          + ((r2.x + r2.y) + (r2.z + r2.w)) + ((r3.x + r3.y) + (r3.z + r3.w))
                          + bias_s[lane];
                float o = xs[c0 + lane] + fmaxf(tot, 0.f);
                float* dst = half ? (T + (size_t)k * EN) : (Hb + (size_t)k * EN);
                AS32(&dst[c0 + lane], __float_as_uint(o));
                if (half && k == 63) out[c0 + lane] = o;   // out row 0 = t_63 (host-read only)
                // T row 0 seed = x0: ATOMIC store — read cross-XCD in phases A/C
                if (!half && k == 1) AS32(&T[c0 + lane], __float_as_uint(xs[c0 + lane]));
            }
            // no trailing barrier: xs/red_t overwrite for k+1 is transitively gated
            // on this block's wave0 store for k (global dataflow).
        }
    }

    // ================= fused tail: A eA B eB C eC logits, 6 flag barriers =================
    unsigned* D0 = FLG;            unsigned* D1 = FLG + 256;
    unsigned* D2 = FLG + 512;      unsigned* D3 = FLG + 768;
    unsigned* D4 = FLG + 1024;     unsigned* D5 = FLG + 1280;
    const int am = tid >> 4;

    // ---- phase A: P[ks] = T[0:63] @ ur1W (K-split 8) ----
    {
        int ks = b >> 5, cc = b & 31;
        int ar = am > 62 ? 62 : am;
        gemm64(T + (size_t)ar * EN, ur1W, ks * 256, cc * 64, P + (size_t)ks * 64 * EN, 8, tid, As, Ws);
    }
    done_bar(D0, b, tid);

    // ---- eA: RT1[m] = T[m] + relu(sum P + ur1b), cols 8b..8b+8 ----
    if (tid < 504) {
        int m = tid >> 3, c = 8 * b + (tid & 7);
        float p = 0.f;
#pragma unroll
        for (int ks = 0; ks < 8; ++ks) p += af(AL32(P + ((size_t)ks * 64 + m) * EN + c));
        float tv = af(AL32(T + (size_t)m * EN + c));
        AS32(RT1 + (size_t)m * EN + c, __float_as_uint(tv + fmaxf(p + ur1b[c], 0.f)));
    }
    done_bar(D1, b, tid);

    // ---- phase B: P[ks] = RT1[0:63] @ ur2W ----
    {
        int ks = b >> 5, cc = b & 31;
        int ar = am > 62 ? 62 : am;
        gemm64(RT1 + (size_t)ar * EN, ur2W, ks * 256, cc * 64, P + (size_t)ks * 64 * EN, 8, tid, As, Ws);
    }
    done_bar(D2, b, tid);

    // ---- eB: out[63-m] = RT1[m] + relu(sum P + ur2b) ----
    if (tid < 504) {
        int m = tid >> 3, c = 8 * b + (tid & 7);
        float p = 0.f;
#pragma unroll
        for (int ks = 0; ks < 8; ++ks) p += af(AL32(P + ((size_t)ks * 64 + m) * EN + c));
        float rv = af(AL32(RT1 + (size_t)m * EN + c));
        AS32(out + (size_t)(63 - m) * EN + c, __float_as_uint(rv + fmaxf(p + ur2b[c], 0.f)));
    }
    done_bar(D3, b, tid);

    // ---- phase C: P[ks*2+mh] = TOPS[mh*64 : +64] @ arW (K-split 4) ----
    // TOPS rows 0..62 = T rows 0..62; row 63 = t_63 = T row 63; rows 64..126 = out rows 1..63
    {
        int ks = b >> 6, mh = (b >> 5) & 1, cc = b & 31;
        int rp = mh * 64 + am; if (rp > 126) rp = 126;
        const float* arow = (rp <= 63) ? (T + (size_t)rp * EN) : (out + (size_t)(rp - 63) * EN);
        gemm64(arow, arW, ks * 512, cc * 64, P + (size_t)(ks * 2 + mh) * 64 * EN, 16, tid, As, Ws);
    }
    done_bar(D4, b, tid);

    // ---- eC: HT[m] = TOPS[m] + relu(sum_ks P[ks*2+mh][m&63] + arb) ----
    if (tid < 1016) {
        int m = tid >> 3, c = 8 * b + (tid & 7);
        int mh = m >> 6, mr = m & 63;
        float p = 0.f;
#pragma unroll
        for (int ks = 0; ks < 4; ++ks) p += af(AL32(P + ((size_t)(ks * 2 + mh) * 64 + mr) * EN + c));
        float tv = (m <= 63) ? af(AL32(T + (size_t)m * EN + c))
                             : af(AL32(out + (size_t)(m - 63) * EN + c));
        AS32(HT + (size_t)m * EN + c, __float_as_uint(tv + fmaxf(p + arb[c], 0.f)));
    }
    done_bar(D5, b, tid);

    // ---- logits: out[131072 + m*2 + c] = HT[m] . aW[:,c] + ab[c], blocks 0..126 ----
    if (b < 127) {
        const float* h = HT + (size_t)b * EN;
        unsigned long long hv = AL64(h + tid * 2);
        float h0 = af((unsigned)hv), h1 = af((unsigned)(hv >> 32));
        float4 w4 = *(const float4*)(aW + (size_t)tid * 4);   // {W[i][0],W[i][1],W[i+1][0],W[i+1][1]}
        float a0 = h0 * w4.x + h1 * w4.z;
        float a1 = h0 * w4.y + h1 * w4.w;
#pragma unroll
        for (int off = 32; off; off >>= 1) { a0 += __shfl_down(a0, off, 64); a1 += __shfl_down(a1, off, 64); }
        if (lane == 0) { lred[wv][0] = a0; lred[wv][1] = a1; }
        __syncthreads();
        if (tid == 0) {
            float s0 = ab[0], s1 = ab[1];
#pragma unroll
            for (int q = 0; q < 16; ++q) { s0 += lred[q][0]; s1 += lred[q][1]; }
            out[64 * EN + b * 2]     = s0;
            out[64 * EN + b * 2 + 1] = s1;
        }
    }
}

extern "C" void kernel_launch(void* const* d_in, const int* in_sizes, int n_in,
                              void* d_out, int out_size, void* d_ws, size_t ws_size,
                              hipStream_t stream)
{
    const float* x0   = (const float*)d_in[0];
    // d_in[1] = fixed_actions (constant 63 reduces + 64 shifts) — structure hardcoded
    const float* arW  = (const float*)d_in[2];
    const float* arb  = (const float*)d_in[3];
    const float* aW   = (const float*)d_in[4];
    const float* ab   = (const float*)d_in[5];
    const float* ul1W = (const float*)d_in[6];
    const float* ul1b = (const float*)d_in[7];
    const float* ul2W = (const float*)d_in[8];
    const float* ul2b = (const float*)d_in[9];
    const float* ur1W = (const float*)d_in[10];
    const float* ur1b = (const float*)d_in[11];
    const float* ur2W = (const float*)d_in[12];
    const float* ur2b = (const float*)d_in[13];

    float* ws  = (float*)d_ws;
    float* out = (float*)d_out;
    float* T   = ws + T_OFF;
    float* Hb  = ws + H_OFF;
    float* RT1 = ws + H_OFF;    // H region is dead after the chain; reused for RT1
    float* HT  = ws + HT_OFF;
    float* P   = ws + P_OFF;
    unsigned* FLG = (unsigned*)(ws + FLG_OFF);

    // one memset: T+H sentinels and flag region (0xFFFFFFFF != 1)
    hipMemsetAsync(ws, 0xFF, (size_t)(129 * EN) * sizeof(float), stream);

    void* args[] = { (void*)&x0, (void*)&ul1W, (void*)&ul1b, (void*)&ul2W, (void*)&ul2b,
                     (void*)&ur1W, (void*)&ur1b, (void*)&ur2W, (void*)&ur2b,
                     (void*)&arW, (void*)&arb, (void*)&aW, (void*)&ab,
                     (void*)&T, (void*)&Hb, (void*)&RT1, (void*)&HT, (void*)&P,
                     (void*)&FLG, (void*)&out };
    hipError_t err = hipLaunchCooperativeKernel(reinterpret_cast<void*>(mega_kernel),
                                                dim3(NCH), dim3(CTH), args, 0, stream);
    if (err != hipSuccess) {
        (void)hipGetLastError();
        // 256 blocks x 1024 threads = exactly 1 block/CU -> co-resident
        mega_kernel<<<dim3(NCH), dim3(CTH), 0, stream>>>(
            x0, ul1W, ul1b, ul2W, ul2b, ur1W, ur1b, ur2W, ur2b,
            arW, arb, aW, ab, T, Hb, RT1, HT, P, FLG, out);
    }
}

// Round 6
// 358.951 us; speedup vs baseline: 1.0987x; 1.0987x over previous
//
#include <hip/hip_runtime.h>

#define EN 2048
#define NCH 256
#define CTH 1024
#define SENT 0xFFFFFFFFu

// ws float offsets (total 768*EN floats = 6.3 MB, proven footprint)
#define T_OFF    0                  // 64 rows (sentinel-polled rows 1..63; row0 = x0, ATOMIC seed)
#define H_OFF    (64 * EN)          // 64 rows (sentinel-polled rows 1..63); reused as RT1 after chain
#define FLG_OFF  (128 * EN)         // 6*256 done-flags (u32) in 1*EN floats
#define HT_OFF   (129 * EN)         // 127 rows -> ends at 256*EN
#define P_OFF    (256 * EN)         // 8 slots x 64 rows x EN -> ends at 768*EN

#define AL64(p)   __hip_atomic_load((const unsigned long long*)(p), __ATOMIC_RELAXED, __HIP_MEMORY_SCOPE_AGENT)
#define AL32(p)   __hip_atomic_load((const unsigned*)(p), __ATOMIC_RELAXED, __HIP_MEMORY_SCOPE_AGENT)
#define AS32(p,v) __hip_atomic_store((unsigned*)(p), (v), __ATOMIC_RELAXED, __HIP_MEMORY_SCOPE_AGENT)
#define AS64(p,v) __hip_atomic_store((unsigned long long*)(p), (v), __ATOMIC_RELAXED, __HIP_MEMORY_SCOPE_AGENT)

__device__ __forceinline__ float af(unsigned u) { return __uint_as_float(u); }
__device__ __forceinline__ unsigned long long pk(float a, float b) {
    return ((unsigned long long)__float_as_uint(b) << 32) | __float_as_uint(a);
}

// fence-free all-blocks-done barrier (proven r5): waves' sc1 stores drained by the
// vmcnt(0) the compiler emits before s_barrier; wave0 sets flag, polls all 256.
__device__ __forceinline__ void done_bar(unsigned* D, int b, int tid) {
    __syncthreads();
    if (tid < 64) {
        if (tid == 0) {
            asm volatile("s_waitcnt vmcnt(0)" ::: "memory");
            AS32(&D[b], 1u);
        }
        const unsigned long long* f = (const unsigned long long*)D;
        const unsigned long long GOOD = 0x0000000100000001ULL;
        for (long it = 0; it < 200000000L; ++it) {
            unsigned long long a = AL64(&f[tid * 2]);
            unsigned long long c = AL64(&f[tid * 2 + 1]);
            if (!__any((int)(a != GOOD || c != GOOD))) break;
        }
    }
    __syncthreads();
}

// 64x64 output tile, 4x4 microtile, in-block K-split-4 (kq = tid>>8).
// Each kq computes NKT k-chunks of 32 into acc; LDS tree-reduce; kq0 stores P.
// A rows read via sc1 atomics (cross-XCD intra-kernel data), W plain.
template<int NKT>
__device__ __forceinline__ void gemm_phase(
    const float* __restrict__ a_stage_row,   // clamped A-row base for this thread's staging role
    const float* __restrict__ W, int kbase, int c0,
    float* __restrict__ Pslot, int tid, float* __restrict__ GB)
{
    const int kq  = tid >> 8;
    const int rem = tid & 255;
    const int ar  = rem >> 2;            // staging A row 0..63
    const int ak8 = (rem & 3) * 8;       // staging A k-offset
    const int wk  = rem >> 3;            // staging W k-row 0..31
    const int wc  = (rem & 7) * 8;       // staging W col
    const int tr  = rem >> 4;            // compute row group 0..15
    const int tc  = rem & 15;            // compute col group 0..15
    float* As = GB + kq * (2 * 32 * 68); // [32][68]
    float* Wt = As + 32 * 68;

    float4 a0 = {0,0,0,0}, a1 = {0,0,0,0}, a2 = {0,0,0,0}, a3 = {0,0,0,0};

    unsigned long long ra0, ra1, ra2, ra3;
    float4 rw0, rw1;
    {
        ra0 = AL64(a_stage_row + kbase + ak8);
        ra1 = AL64(a_stage_row + kbase + ak8 + 2);
        ra2 = AL64(a_stage_row + kbase + ak8 + 4);
        ra3 = AL64(a_stage_row + kbase + ak8 + 6);
        const float* wp = W + (size_t)(kbase + wk) * EN + c0 + wc;
        rw0 = *(const float4*)wp; rw1 = *(const float4*)(wp + 4);
    }
    for (int kt = 0; kt < NKT; ++kt) {
        __syncthreads();
        As[(ak8+0)*68+ar] = af((unsigned)ra0); As[(ak8+1)*68+ar] = af((unsigned)(ra0>>32));
        As[(ak8+2)*68+ar] = af((unsigned)ra1); As[(ak8+3)*68+ar] = af((unsigned)(ra1>>32));
        As[(ak8+4)*68+ar] = af((unsigned)ra2); As[(ak8+5)*68+ar] = af((unsigned)(ra2>>32));
        As[(ak8+6)*68+ar] = af((unsigned)ra3); As[(ak8+7)*68+ar] = af((unsigned)(ra3>>32));
        *(float4*)&Wt[wk*68+wc]     = rw0;
        *(float4*)&Wt[wk*68+wc+4]  = rw1;
        __syncthreads();
        if (kt + 1 < NKT) {
            int kb = kbase + (kt + 1) * 32;
            ra0 = AL64(a_stage_row + kb + ak8);
            ra1 = AL64(a_stage_row + kb + ak8 + 2);
            ra2 = AL64(a_stage_row + kb + ak8 + 4);
            ra3 = AL64(a_stage_row + kb + ak8 + 6);
            const float* wp = W + (size_t)(kb + wk) * EN + c0 + wc;
            rw0 = *(const float4*)wp; rw1 = *(const float4*)(wp + 4);
        }
#pragma unroll
        for (int kk = 0; kk < 32; ++kk) {
            float4 av = *(const float4*)&As[kk*68 + tr*4];
            float4 wv = *(const float4*)&Wt[kk*68 + tc*4];
            a0.x += av.x*wv.x; a0.y += av.x*wv.y; a0.z += av.x*wv.z; a0.w += av.x*wv.w;
            a1.x += av.y*wv.x; a1.y += av.y*wv.y; a1.z += av.y*wv.z; a1.w += av.y*wv.w;
            a2.x += av.z*wv.x; a2.y += av.z*wv.y; a2.z += av.z*wv.z; a2.w += av.z*wv.w;
            a3.x += av.w*wv.x; a3.y += av.w*wv.y; a3.z += av.w*wv.z; a3.w += av.w*wv.w;
        }
    }
    // cross-kq reduce: kq1..3 dump acc into GB scratch [3][16][256], kq0 sums + stores
    __syncthreads();
    if (kq > 0) {
        float* d = GB + (kq - 1) * 4096 + rem;
        d[0*256]=a0.x; d[1*256]=a0.y; d[2*256]=a0.z;  d[3*256]=a0.w;
        d[4*256]=a1.x; d[5*256]=a1.y; d[6*256]=a1.z;  d[7*256]=a1.w;
        d[8*256]=a2.x; d[9*256]=a2.y; d[10*256]=a2.z; d[11*256]=a2.w;
        d[12*256]=a3.x; d[13*256]=a3.y; d[14*256]=a3.z; d[15*256]=a3.w;
    }
    __syncthreads();
    if (kq == 0) {
#pragma unroll
        for (int q = 0; q < 3; ++q) {
            const float* s = GB + q * 4096 + rem;
            a0.x+=s[0*256]; a0.y+=s[1*256]; a0.z+=s[2*256];  a0.w+=s[3*256];
            a1.x+=s[4*256]; a1.y+=s[5*256]; a1.z+=s[6*256];  a1.w+=s[7*256];
            a2.x+=s[8*256]; a2.y+=s[9*256]; a2.z+=s[10*256]; a2.w+=s[11*256];
            a3.x+=s[12*256]; a3.y+=s[13*256]; a3.z+=s[14*256]; a3.w+=s[15*256];
        }
        float* p0 = Pslot + (size_t)(tr*4    ) * EN + c0 + tc*4;
        float* p1 = Pslot + (size_t)(tr*4 + 1) * EN + c0 + tc*4;
        float* p2 = Pslot + (size_t)(tr*4 + 2) * EN + c0 + tc*4;
        float* p3 = Pslot + (size_t)(tr*4 + 3) * EN + c0 + tc*4;
        AS64(p0, pk(a0.x, a0.y)); AS64(p0 + 2, pk(a0.z, a0.w));
        AS64(p1, pk(a1.x, a1.y)); AS64(p1 + 2, pk(a1.z, a1.w));
        AS64(p2, pk(a2.x, a2.y)); AS64(p2 + 2, pk(a2.z, a2.w));
        AS64(p3, pk(a3.x, a3.y)); AS64(p3 + 2, pk(a3.z, a3.w));
    }
    __syncthreads();
}

__global__ __launch_bounds__(CTH, 1) void mega_kernel(
    const float* __restrict__ x0,
    const float* __restrict__ ul1W, const float* __restrict__ ul1b,
    const float* __restrict__ ul2W, const float* __restrict__ ul2b,
    const float* __restrict__ ur1W, const float* __restrict__ ur1b,
    const float* __restrict__ ur2W, const float* __restrict__ ur2b,
    const float* __restrict__ arW,  const float* __restrict__ arb,
    const float* __restrict__ aW,   const float* __restrict__ ab,
    float* __restrict__ T, float* __restrict__ Hb, float* __restrict__ RT1,
    float* __restrict__ HT, float* __restrict__ P, unsigned* __restrict__ FLG,
    float* __restrict__ out)
{
    __shared__ __align__(16) float xs[EN];
    __shared__ __align__(16) float red_t[16][20];
    __shared__ float bias_s[16];
    __shared__ __align__(16) float GB[4 * 2 * 32 * 68];   // gemm staging + reduce scratch (68 KB)
    __shared__ float lred[16][2];

    const int tid  = threadIdx.x;
    const int b    = blockIdx.x;
    const int lane = tid & 63;
    const int wv   = tid >> 6;

    // ================= chain: 63 steps x 2 res-layers, pure dataflow =================
    {
        const int half  = b >> 7;         // 0 -> ul1 (produce H), 1 -> ul2 (produce T)
        const int idx   = b & 127;
        const int c0    = idx * 16;
        const int col   = tid & 15;
        const int chunk = tid >> 4;       // 0..63
        const float* Wg = half ? ul2W : ul1W;
        const float* bg = half ? ul2b : ul1b;

        float4 w[8];
#pragma unroll
        for (int j = 0; j < 8; ++j) {
            const float* wp = Wg + (size_t)(chunk * 32 + j * 4) * EN + c0 + col;
            w[j].x = wp[0]; w[j].y = wp[EN]; w[j].z = wp[2 * EN]; w[j].w = wp[3 * EN];
        }
        if (tid < 16) bias_s[tid] = bg[c0 + tid];

        for (int k = 1; k <= 63; ++k) {
            if (half == 0 && k == 1) {
                reinterpret_cast<float2*>(xs)[tid] = reinterpret_cast<const float2*>(x0)[tid];
            } else {
                const float* src = half ? (Hb + (size_t)k * EN) : (T + (size_t)(k - 1) * EN);
                const unsigned long long* s64 =
                    reinterpret_cast<const unsigned long long*>(src) + (size_t)wv * 64 + lane;
                unsigned long long v;
                for (;;) {                               // 1-deep poll (r3-proven)
                    v = AL64(s64);
                    unsigned lo = (unsigned)v, hi = (unsigned)(v >> 32);
                    if (!__any((int)(lo == SENT || hi == SENT))) break;
                }
                float2 xv;
                xv.x = af((unsigned)v); xv.y = af((unsigned)(v >> 32));
                reinterpret_cast<float2*>(xs)[tid] = xv;
            }
            __syncthreads();

            float s = 0.f;
            const float4* xv4 = reinterpret_cast<const float4*>(xs) + chunk * 8;
#pragma unroll
            for (int j = 0; j < 8; ++j) {
                float4 x4 = xv4[j];
                s += x4.x * w[j].x + x4.y * w[j].y + x4.z * w[j].z + x4.w * w[j].w;
            }
            s += __shfl_xor(s, 16, 64);
            s += __shfl_xor(s, 32, 64);
            if (lane < 16) red_t[lane][wv] = s;
            __syncthreads();

            if (wv == 0 && lane < 16) {
                float4 r0 = *(const float4*)&red_t[lane][0];
                float4 r1 = *(const float4*)&red_t[lane][4];
                float4 r2 = *(const float4*)&red_t[lane][8];
                float4 r3 = *(const float4*)&red_t[lane][12];
                float tot = ((r0.x + r0.y) + (r0.z + r0.w)) + ((r1.x + r1.y) + (r1.z + r1.w))
                          + ((r2.x + r2.y) + (r2.z + r2.w)) + ((r3.x + r3.y) + (r3.z + r3.w))
                          + bias_s[lane];
                float o = xs[c0 + lane] + fmaxf(tot, 0.f);
                float* dst = half ? (T + (size_t)k * EN) : (Hb + (size_t)k * EN);
                AS32(&dst[c0 + lane], __float_as_uint(o));
                if (half && k == 63) out[c0 + lane] = o;   // out row 0 (host-read only)
                if (!half && k == 1) AS32(&T[c0 + lane], __float_as_uint(xs[c0 + lane])); // T row0 seed
            }
            // no trailing barrier: xs/red_t overwrite for k+1 is transitively gated
            // on this block's wave0 store for k (global dataflow).
        }
    }

    // ================= fused tail: A eA B eB C eC logits, 6 flag barriers =================
    unsigned* D0 = FLG;            unsigned* D1 = FLG + 256;
    unsigned* D2 = FLG + 512;      unsigned* D3 = FLG + 768;
    unsigned* D4 = FLG + 1024;     unsigned* D5 = FLG + 1280;

    // ---- phase A: P[ks] = T[0:63] @ ur1W   (grid: 32 cc x 8 ks; in-block kq4) ----
    {
        const int rem = tid & 255, kq = tid >> 8;
        int ar = rem >> 2; if (ar > 62) ar = 62;
        int cc = b & 31, ks = b >> 5;
        gemm_phase<2>(T + (size_t)ar * EN, ur1W, ks * 256 + kq * 64, cc * 64,
                      P + (size_t)ks * 64 * EN, tid, GB);
    }
    done_bar(D0, b, tid);

    // ---- eA: RT1[m] = T[m] + relu(sum P + ur1b), cols 8b..8b+8 ----
    if (tid < 504) {
        int m = tid >> 3, c = 8 * b + (tid & 7);
        float p = 0.f;
#pragma unroll
        for (int ks = 0; ks < 8; ++ks) p += af(AL32(P + ((size_t)ks * 64 + m) * EN + c));
        float tv = af(AL32(T + (size_t)m * EN + c));
        AS32(RT1 + (size_t)m * EN + c, __float_as_uint(tv + fmaxf(p + ur1b[c], 0.f)));
    }
    done_bar(D1, b, tid);

    // ---- phase B: P[ks] = RT1[0:63] @ ur2W ----
    {
        const int rem = tid & 255, kq = tid >> 8;
        int ar = rem >> 2; if (ar > 62) ar = 62;
        int cc = b & 31, ks = b >> 5;
        gemm_phase<2>(RT1 + (size_t)ar * EN, ur2W, ks * 256 + kq * 64, cc * 64,
                      P + (size_t)ks * 64 * EN, tid, GB);
    }
    done_bar(D2, b, tid);

    // ---- eB: out[63-m] = RT1[m] + relu(sum P + ur2b) ----
    if (tid < 504) {
        int m = tid >> 3, c = 8 * b + (tid & 7);
        float p = 0.f;
#pragma unroll
        for (int ks = 0; ks < 8; ++ks) p += af(AL32(P + ((size_t)ks * 64 + m) * EN + c));
        float rv = af(AL32(RT1 + (size_t)m * EN + c));
        AS32(out + (size_t)(63 - m) * EN + c, __float_as_uint(rv + fmaxf(p + ur2b[c], 0.f)));
    }
    done_bar(D3, b, tid);

    // ---- phase C: P[ks*2+mh] = TOPS[mh*64:+64] @ arW  (grid: 32 cc x 2 mh x 4 ks) ----
    // TOPS rows 0..63 = T rows 0..63 (row 63 = t_63); rows 64..126 = out rows 1..63
    {
        const int rem = tid & 255, kq = tid >> 8;
        int cc = b & 31, mh = (b >> 5) & 1, ks = b >> 6;
        int rp = mh * 64 + (rem >> 2); if (rp > 126) rp = 126;
        const float* arow = (rp <= 63) ? (T + (size_t)rp * EN) : (out + (size_t)(rp - 63) * EN);
        gemm_phase<4>(arow, arW, ks * 512 + kq * 128, cc * 64,
                      P + (size_t)(ks * 2 + mh) * 64 * EN, tid, GB);
    }
    done_bar(D4, b, tid);

    // ---- eC: HT[m] = TOPS[m] + relu(sum_ks P[ks*2+mh][m&63] + arb) ----
    if (tid < 1016) {
        int m = tid >> 3, c = 8 * b + (tid & 7);
        int mh = m >> 6, mr = m & 63;
        float p = 0.f;
#pragma unroll
        for (int ks = 0; ks < 4; ++ks) p += af(AL32(P + ((size_t)(ks * 2 + mh) * 64 + mr) * EN + c));
        float tv = (m <= 63) ? af(AL32(T + (size_t)m * EN + c))
                             : af(AL32(out + (size_t)(m - 63) * EN + c));
        AS32(HT + (size_t)m * EN + c, __float_as_uint(tv + fmaxf(p + arb[c], 0.f)));
    }
    done_bar(D5, b, tid);

    // ---- logits: out[131072 + m*2 + c] = HT[m] . aW[:,c] + ab[c], blocks 0..126 ----
    if (b < 127) {
        const float* h = HT + (size_t)b * EN;
        unsigned long long hv = AL64(h + tid * 2);
        float h0 = af((unsigned)hv), h1 = af((unsigned)(hv >> 32));
        float4 w4 = *(const float4*)(aW + (size_t)tid * 4);   // {W[2t][0],W[2t][1],W[2t+1][0],W[2t+1][1]}
        float s0 = h0 * w4.x + h1 * w4.z;
        float s1 = h0 * w4.y + h1 * w4.w;
#pragma unroll
        for (int off = 32; off; off >>= 1) { s0 += __shfl_down(s0, off, 64); s1 += __shfl_down(s1, off, 64); }
        if (lane == 0) { lred[wv][0] = s0; lred[wv][1] = s1; }
        __syncthreads();
        if (tid == 0) {
            float t0 = ab[0], t1 = ab[1];
#pragma unroll
            for (int q = 0; q < 16; ++q) { t0 += lred[q][0]; t1 += lred[q][1]; }
            out[64 * EN + b * 2]     = t0;
            out[64 * EN + b * 2 + 1] = t1;
        }
    }
}

extern "C" void kernel_launch(void* const* d_in, const int* in_sizes, int n_in,
                              void* d_out, int out_size, void* d_ws, size_t ws_size,
                              hipStream_t stream)
{
    const float* x0   = (const float*)d_in[0];
    // d_in[1] = fixed_actions (constant 63 reduces + 64 shifts) — structure hardcoded
    const float* arW  = (const float*)d_in[2];
    const float* arb  = (const float*)d_in[3];
    const float* aW   = (const float*)d_in[4];
    const float* ab   = (const float*)d_in[5];
    const float* ul1W = (const float*)d_in[6];
    const float* ul1b = (const float*)d_in[7];
    const float* ul2W = (const float*)d_in[8];
    const float* ul2b = (const float*)d_in[9];
    const float* ur1W = (const float*)d_in[10];
    const float* ur1b = (const float*)d_in[11];
    const float* ur2W = (const float*)d_in[12];
    const float* ur2b = (const float*)d_in[13];

    float* ws  = (float*)d_ws;
    float* out = (float*)d_out;
    float* T   = ws + T_OFF;
    float* Hb  = ws + H_OFF;
    float* RT1 = ws + H_OFF;    // H region dead after chain; reused for RT1
    float* HT  = ws + HT_OFF;
    float* P   = ws + P_OFF;
    unsigned* FLG = (unsigned*)(ws + FLG_OFF);

    // one memset: T+H sentinels and flag region (0xFFFFFFFF != 1)
    hipMemsetAsync(ws, 0xFF, (size_t)(129 * EN) * sizeof(float), stream);

    void* args[] = { (void*)&x0, (void*)&ul1W, (void*)&ul1b, (void*)&ul2W, (void*)&ul2b,
                     (void*)&ur1W, (void*)&ur1b, (void*)&ur2W, (void*)&ur2b,
                     (void*)&arW, (void*)&arb, (void*)&aW, (void*)&ab,
                     (void*)&T, (void*)&Hb, (void*)&RT1, (void*)&HT, (void*)&P,
                     (void*)&FLG, (void*)&out };
    hipError_t err = hipLaunchCooperativeKernel(reinterpret_cast<void*>(mega_kernel),
                                                dim3(NCH), dim3(CTH), args, 0, stream);
    if (err != hipSuccess) {
        (void)hipGetLastError();
        // 256 blocks x 1024 threads = exactly 1 block/CU -> co-resident
        mega_kernel<<<dim3(NCH), dim3(CTH), 0, stream>>>(
            x0, ul1W, ul1b, ul2W, ul2b, ur1W, ur1b, ur2W, ur2b,
            arW, arb, aW, ab, T, Hb, RT1, HT, P, FLG, out);
    }
}

// Round 8
// 332.166 us; speedup vs baseline: 1.1873x; 1.0806x over previous
//
#include <hip/hip_runtime.h>

#define EN 2048
#define NCH 256
#define CTH 1024
#define SENT 0xFFFFFFFFu

typedef float f32x4 __attribute__((ext_vector_type(4)));
typedef float f32x2 __attribute__((ext_vector_type(2)));

// ws float offsets (total 768*EN floats = 6.29 MB — proven-fitting footprint)
#define T_OFF    0                  // 64 rows (sentinel rows 1..63; row0 = x0 seed, atomic)
#define H_OFF    (64 * EN)          // 64 rows (sentinel rows 1..63); reused as RT1 after chain
#define FLG_OFF  (128 * EN)         // 6*256 done-flags (u32) in 1*EN floats
#define HT_OFF   (129 * EN)         // 127 rows -> ends at 256*EN
#define P_OFF    (256 * EN)         // 8 slots x 64 rows x EN -> ends at 768*EN

#define AL64(p)   __hip_atomic_load((const unsigned long long*)(p), __ATOMIC_RELAXED, __HIP_MEMORY_SCOPE_AGENT)
#define AS32(p,v) __hip_atomic_store((unsigned*)(p), (v), __ATOMIC_RELAXED, __HIP_MEMORY_SCOPE_AGENT)

// 16B device-coherent load/store (sc1 = agent scope)
#define GL16(d, p) asm volatile("global_load_dwordx4 %0, %1, off sc1" : "=&v"(d) : "v"(p) : "memory")
#define ST16(p, d) asm volatile("global_store_dwordx4 %0, %1, off sc1" :: "v"(p), "v"(d) : "memory")

__device__ __forceinline__ float af(unsigned u) { return __uint_as_float(u); }

// fence-free all-blocks-done barrier: every thread drains its own vmem (covers
// asm-issued ST16/GL16 the compiler's waitcnt pass can't see), block barrier,
// then wave0 sets this block's flag and polls all 256 flags (sc1).
__device__ __forceinline__ void done_bar(unsigned* D, int b, int tid) {
    asm volatile("s_waitcnt vmcnt(0)" ::: "memory");
    __syncthreads();
    if (tid < 64) {
        if (tid == 0) AS32(&D[b], 1u);
        const unsigned long long* f = (const unsigned long long*)D;
        const unsigned long long GOOD = 0x0000000100000001ULL;
        for (long it = 0; it < 200000000L; ++it) {
            unsigned long long a = AL64(&f[tid * 2]);
            unsigned long long c = AL64(&f[tid * 2 + 1]);
            if (!__any((int)(a != GOOD || c != GOOD))) break;
        }
    }
    __syncthreads();
}

// 64x64 output tile, 4x4 microtile, in-block K-split-4 (kq = tid>>8).
// r6-proven geometry; staging A via 16B sc1 asm loads, P stores via 16B sc1.
template<int NKT>
__device__ __forceinline__ void gemm64(
    const float* __restrict__ Arow,   // per-thread resolved + clamped A row base
    const float* __restrict__ W, int kbase, int c0,
    float* __restrict__ Pslot, int tid, float* __restrict__ GB)
{
    const int kq  = tid >> 8;
    const int rem = tid & 255;
    const int am  = rem >> 2;            // staging A row 0..63
    const int ak8 = (rem & 3) * 8;       // staging A k-offset (8 floats)
    const int wk  = rem >> 3;            // staging W k-row 0..31
    const int wq  = rem & 7;             // staging W col-octet
    const int tr  = rem >> 4, tc = rem & 15;
    float* As = GB + kq * 4352;          // [32][68]
    float* Wt = As + 2176;               // [32][68]

    f32x4 acc0 = (f32x4)(0.f), acc1 = (f32x4)(0.f), acc2 = (f32x4)(0.f), acc3 = (f32x4)(0.f);

    for (int kt = 0; kt < NKT; ++kt) {
        int kb = kbase + kt * 32;
        f32x4 ra0, ra1;
        GL16(ra0, Arow + kb + ak8);
        GL16(ra1, Arow + kb + ak8 + 4);
        const float* wp = W + (size_t)(kb + wk) * EN + c0 + wq * 8;
        f32x4 rw0 = *(const f32x4*)wp;
        f32x4 rw1 = *(const f32x4*)(wp + 4);
        asm volatile("s_waitcnt vmcnt(0)" : "+v"(ra0), "+v"(ra1) :: "memory");
        __syncthreads();
        As[(ak8 + 0) * 68 + am] = ra0.x; As[(ak8 + 1) * 68 + am] = ra0.y;
        As[(ak8 + 2) * 68 + am] = ra0.z; As[(ak8 + 3) * 68 + am] = ra0.w;
        As[(ak8 + 4) * 68 + am] = ra1.x; As[(ak8 + 5) * 68 + am] = ra1.y;
        As[(ak8 + 6) * 68 + am] = ra1.z; As[(ak8 + 7) * 68 + am] = ra1.w;
        *(f32x4*)&Wt[wk * 68 + wq * 8]     = rw0;
        *(f32x4*)&Wt[wk * 68 + wq * 8 + 4] = rw1;
        __syncthreads();
#pragma unroll
        for (int kk = 0; kk < 32; ++kk) {
            f32x4 av  = *(const f32x4*)&As[kk * 68 + tr * 4];
            f32x4 wv4 = *(const f32x4*)&Wt[kk * 68 + tc * 4];
            acc0 += av.x * wv4; acc1 += av.y * wv4;
            acc2 += av.z * wv4; acc3 += av.w * wv4;
        }
    }
    // cross-kq reduce: kq1..3 dump 16 floats into region (kq-1); kq0 sums + stores
    __syncthreads();
    if (kq) {
        float* d = GB + (kq - 1) * 4352 + rem;
        d[0*256]=acc0.x;  d[1*256]=acc0.y;  d[2*256]=acc0.z;  d[3*256]=acc0.w;
        d[4*256]=acc1.x;  d[5*256]=acc1.y;  d[6*256]=acc1.z;  d[7*256]=acc1.w;
        d[8*256]=acc2.x;  d[9*256]=acc2.y;  d[10*256]=acc2.z; d[11*256]=acc2.w;
        d[12*256]=acc3.x; d[13*256]=acc3.y; d[14*256]=acc3.z; d[15*256]=acc3.w;
    }
    __syncthreads();
    if (kq == 0) {
#pragma unroll
        for (int q = 0; q < 3; ++q) {
            const float* s = GB + q * 4352 + rem;
            acc0.x+=s[0*256];  acc0.y+=s[1*256];  acc0.z+=s[2*256];  acc0.w+=s[3*256];
            acc1.x+=s[4*256];  acc1.y+=s[5*256];  acc1.z+=s[6*256];  acc1.w+=s[7*256];
            acc2.x+=s[8*256];  acc2.y+=s[9*256];  acc2.z+=s[10*256]; acc2.w+=s[11*256];
            acc3.x+=s[12*256]; acc3.y+=s[13*256]; acc3.z+=s[14*256]; acc3.w+=s[15*256];
        }
        ST16(Pslot + (size_t)(tr * 4 + 0) * EN + c0 + tc * 4, acc0);
        ST16(Pslot + (size_t)(tr * 4 + 1) * EN + c0 + tc * 4, acc1);
        ST16(Pslot + (size_t)(tr * 4 + 2) * EN + c0 + tc * 4, acc2);
        ST16(Pslot + (size_t)(tr * 4 + 3) * EN + c0 + tc * 4, acc3);
    }
    __syncthreads();
}

__global__ __launch_bounds__(CTH, 1) void mega_kernel(
    const float* __restrict__ x0,
    const float* __restrict__ ul1W, const float* __restrict__ ul1b,
    const float* __restrict__ ul2W, const float* __restrict__ ul2b,
    const float* __restrict__ ur1W, const float* __restrict__ ur1b,
    const float* __restrict__ ur2W, const float* __restrict__ ur2b,
    const float* __restrict__ arW,  const float* __restrict__ arb,
    const float* __restrict__ aW,   const float* __restrict__ ab,
    float* __restrict__ T, float* __restrict__ Hb, float* __restrict__ RT1,
    float* __restrict__ HT, float* __restrict__ P, unsigned* __restrict__ FLG,
    float* __restrict__ out)
{
    __shared__ __align__(16) float xs[EN];
    __shared__ __align__(16) float red_t[16][20];
    __shared__ float bias_s[16];
    __shared__ __align__(16) float GB[4 * 4352];   // 69.6 KB gemm staging/reduce
    __shared__ float lred[16][2];
    __shared__ unsigned cnt;

    const int tid  = threadIdx.x;
    const int b    = blockIdx.x;
    const int lane = tid & 63;
    const int wv   = tid >> 6;

    // ========== chain: 63 steps x 2 res-layers, pure dataflow, 0-barrier hops ==========
    {
        const int half  = b >> 7;         // 0 -> ul1 (produce H), 1 -> ul2 (produce T)
        const int idx   = b & 127;
        const int c0    = idx * 16;
        const int col   = tid & 15;
        const int chunk = tid >> 4;       // 0..63
        const float* Wg = half ? ul2W : ul1W;
        const float* bg = half ? ul2b : ul1b;

        f32x4 w[8];
#pragma unroll
        for (int j = 0; j < 8; ++j) {
            const float* wp = Wg + (size_t)(chunk * 32 + j * 4) * EN + c0 + col;
            w[j].x = wp[0]; w[j].y = wp[EN]; w[j].z = wp[2 * EN]; w[j].w = wp[3 * EN];
        }
        if (tid < 16) bias_s[tid] = bg[c0 + tid];
        if (tid == 0) cnt = 0;
        __syncthreads();

        for (int k = 1; k <= 63; ++k) {
            if (half == 0 && k == 1) {
                reinterpret_cast<f32x2*>(xs)[tid] = reinterpret_cast<const f32x2*>(x0)[tid];
            } else {
                const float* src = half ? (Hb + (size_t)k * EN) : (T + (size_t)(k - 1) * EN);
                const unsigned long long* s64 =
                    reinterpret_cast<const unsigned long long*>(src) + (size_t)wv * 64 + lane;
                unsigned long long v;
                for (;;) {                               // 1-deep poll (r3-proven, no in-flight exit)
                    v = AL64(s64);
                    unsigned lo = (unsigned)v, hi = (unsigned)(v >> 32);
                    if (!__any((int)(lo == SENT || hi == SENT))) break;
                }
                f32x2 xv; xv.x = af((unsigned)v); xv.y = af((unsigned)(v >> 32));
                reinterpret_cast<f32x2*>(xs)[tid] = xv;  // own wave's 128-float section only
            }

            // wave-local dot over own 128-float section (no block barrier)
            float s = 0.f;
            const f32x4* xv4 = reinterpret_cast<const f32x4*>(xs) + chunk * 8;
#pragma unroll
            for (int j = 0; j < 8; ++j) {
                f32x4 x4 = xv4[j];
                s += x4.x * w[j].x + x4.y * w[j].y + x4.z * w[j].z + x4.w * w[j].w;
            }
            s += __shfl_xor(s, 16, 64);
            s += __shfl_xor(s, 32, 64);
            if (lane < 16) red_t[lane][wv] = s;
            if (lane == 0)
                __hip_atomic_fetch_add(&cnt, 1u, __ATOMIC_RELEASE, __HIP_MEMORY_SCOPE_WORKGROUP);

            if (wv == 0) {
                unsigned tgt = 16u * (unsigned)k;
                while (__hip_atomic_load(&cnt, __ATOMIC_ACQUIRE, __HIP_MEMORY_SCOPE_WORKGROUP) < tgt) {}
                if (lane < 16) {
                    f32x4 r0 = *(const f32x4*)&red_t[lane][0];
                    f32x4 r1 = *(const f32x4*)&red_t[lane][4];
                    f32x4 r2 = *(const f32x4*)&red_t[lane][8];
                    f32x4 r3 = *(const f32x4*)&red_t[lane][12];
                    float tot = ((r0.x + r0.y) + (r0.z + r0.w)) + ((r1.x + r1.y) + (r1.z + r1.w))
                              + ((r2.x + r2.y) + (r2.z + r2.w)) + ((r3.x + r3.y) + (r3.z + r3.w))
                              + bias_s[lane];
                    float o = xs[c0 + lane] + fmaxf(tot, 0.f);
                    float* dst = half ? (T + (size_t)k * EN) : (Hb + (size_t)k * EN);
                    AS32(&dst[c0 + lane], __float_as_uint(o));
                    if (half && k == 63) out[c0 + lane] = o;            // out row 0 (host-read)
                    if (!half && k == 1) AS32(&T[c0 + lane], __float_as_uint(xs[c0 + lane]));
                }
            }
            // no trailing barrier: xs/red_t overwrite at k+1 is transitively gated on
            // this block's wave0 store for k via the cross-block dataflow.
        }
    }

    // ========== fused tail: A eA B eB C eC logits, 6 flag barriers ==========
    unsigned* D0 = FLG;        unsigned* D1 = FLG + 256;  unsigned* D2 = FLG + 512;
    unsigned* D3 = FLG + 768;  unsigned* D4 = FLG + 1024; unsigned* D5 = FLG + 1280;
    const int rem = tid & 255;
    const int sar = rem >> 2;

    // ---- phase A: P[ks] = T[0:63] @ ur1W   (grid: 32 cc x 8 ks; in-block kq4 x NKT2) ----
    {
        int cc = b & 31, ks = b >> 5, kq = tid >> 8;
        int ar = sar > 62 ? 62 : sar;
        gemm64<2>(T + (size_t)ar * EN, ur1W, ks * 256 + kq * 64, cc * 64,
                  P + (size_t)ks * 64 * EN, tid, GB);
    }
    done_bar(D0, b, tid);

    // ---- eA: RT1[m] = T[m] + relu(sum_s P[s] + ur1b), this block's 8 cols ----
    if (tid < 126) {
        int m = tid >> 1, qd = tid & 1;
        int c = 8 * b + qd * 4;
        const float* pc = P + (size_t)m * EN + c;
        f32x4 v0, v1, v2, v3, v4, v5, v6, v7, tv;
        GL16(v0, pc + (size_t)0 * 64 * EN); GL16(v1, pc + (size_t)1 * 64 * EN);
        GL16(v2, pc + (size_t)2 * 64 * EN); GL16(v3, pc + (size_t)3 * 64 * EN);
        GL16(v4, pc + (size_t)4 * 64 * EN); GL16(v5, pc + (size_t)5 * 64 * EN);
        GL16(v6, pc + (size_t)6 * 64 * EN); GL16(v7, pc + (size_t)7 * 64 * EN);
        GL16(tv, T + (size_t)m * EN + c);
        asm volatile("s_waitcnt vmcnt(0)"
            : "+v"(v0),"+v"(v1),"+v"(v2),"+v"(v3),"+v"(v4),"+v"(v5),"+v"(v6),"+v"(v7),"+v"(tv)
            :: "memory");
        f32x4 sum = ((v0 + v1) + (v2 + v3)) + ((v4 + v5) + (v6 + v7));
        f32x4 bb = *(const f32x4*)(ur1b + c);
        f32x4 r;
        r.x = tv.x + fmaxf(sum.x + bb.x, 0.f); r.y = tv.y + fmaxf(sum.y + bb.y, 0.f);
        r.z = tv.z + fmaxf(sum.z + bb.z, 0.f); r.w = tv.w + fmaxf(sum.w + bb.w, 0.f);
        ST16(RT1 + (size_t)m * EN + c, r);
    }
    done_bar(D1, b, tid);

    // ---- phase B: P[ks] = RT1[0:63] @ ur2W ----
    {
        int cc = b & 31, ks = b >> 5, kq = tid >> 8;
        int ar = sar > 62 ? 62 : sar;
        gemm64<2>(RT1 + (size_t)ar * EN, ur2W, ks * 256 + kq * 64, cc * 64,
                  P + (size_t)ks * 64 * EN, tid, GB);
    }
    done_bar(D2, b, tid);

    // ---- eB: out[63-m] = RT1[m] + relu(sum_s P[s] + ur2b) ----
    if (tid < 126) {
        int m = tid >> 1, qd = tid & 1;
        int c = 8 * b + qd * 4;
        const float* pc = P + (size_t)m * EN + c;
        f32x4 v0, v1, v2, v3, v4, v5, v6, v7, tv;
        GL16(v0, pc + (size_t)0 * 64 * EN); GL16(v1, pc + (size_t)1 * 64 * EN);
        GL16(v2, pc + (size_t)2 * 64 * EN); GL16(v3, pc + (size_t)3 * 64 * EN);
        GL16(v4, pc + (size_t)4 * 64 * EN); GL16(v5, pc + (size_t)5 * 64 * EN);
        GL16(v6, pc + (size_t)6 * 64 * EN); GL16(v7, pc + (size_t)7 * 64 * EN);
        GL16(tv, RT1 + (size_t)m * EN + c);
        asm volatile("s_waitcnt vmcnt(0)"
            : "+v"(v0),"+v"(v1),"+v"(v2),"+v"(v3),"+v"(v4),"+v"(v5),"+v"(v6),"+v"(v7),"+v"(tv)
            :: "memory");
        f32x4 sum = ((v0 + v1) + (v2 + v3)) + ((v4 + v5) + (v6 + v7));
        f32x4 bb = *(const f32x4*)(ur2b + c);
        f32x4 r;
        r.x = tv.x + fmaxf(sum.x + bb.x, 0.f); r.y = tv.y + fmaxf(sum.y + bb.y, 0.f);
        r.z = tv.z + fmaxf(sum.z + bb.z, 0.f); r.w = tv.w + fmaxf(sum.w + bb.w, 0.f);
        ST16(out + (size_t)(63 - m) * EN + c, r);
    }
    done_bar(D3, b, tid);

    // ---- phase C: P[ks*2+mh] = TOPS[mh*64:+64] @ arW  (grid: 32 cc x 2 mh x 4 ks; NKT4) ----
    // TOPS rows 0..63 = T rows 0..63 (row 63 = t_63); rows 64..126 = out rows 1..63
    {
        int cc = b & 31, mh = (b >> 5) & 1, ks = b >> 6, kq = tid >> 8;
        int rp = mh * 64 + sar; if (rp > 126) rp = 126;
        const float* arow = (rp <= 63) ? (T + (size_t)rp * EN) : (out + (size_t)(rp - 63) * EN);
        gemm64<4>(arow, arW, ks * 512 + kq * 128, cc * 64,
                  P + (size_t)(ks * 2 + mh) * 64 * EN, tid, GB);
    }
    done_bar(D4, b, tid);

    // ---- eC: HT[m] = TOPS[m] + relu(sum_ks P[ks*2+mh] + arb) ----
    if (tid < 254) {
        int m = tid >> 1, qd = tid & 1;
        int c = 8 * b + qd * 4;
        int mh = m >> 6, mr = m & 63;
        f32x4 v0, v1, v2, v3, tv;
        GL16(v0, P + ((size_t)(0 * 2 + mh) * 64 + mr) * EN + c);
        GL16(v1, P + ((size_t)(1 * 2 + mh) * 64 + mr) * EN + c);
        GL16(v2, P + ((size_t)(2 * 2 + mh) * 64 + mr) * EN + c);
        GL16(v3, P + ((size_t)(3 * 2 + mh) * 64 + mr) * EN + c);
        const float* trow = (m <= 63) ? (T + (size_t)m * EN) : (out + (size_t)(m - 63) * EN);
        GL16(tv, trow + c);
        asm volatile("s_waitcnt vmcnt(0)"
            : "+v"(v0),"+v"(v1),"+v"(v2),"+v"(v3),"+v"(tv) :: "memory");
        f32x4 sum = (v0 + v1) + (v2 + v3);
        f32x4 bb = *(const f32x4*)(arb + c);
        f32x4 r;
        r.x = tv.x + fmaxf(sum.x + bb.x, 0.f); r.y = tv.y + fmaxf(sum.y + bb.y, 0.f);
        r.z = tv.z + fmaxf(sum.z + bb.z, 0.f); r.w = tv.w + fmaxf(sum.w + bb.w, 0.f);
        ST16(HT + (size_t)m * EN + c, r);
    }
    done_bar(D5, b, tid);

    // ---- logits: out[131072 + m*2 + c] = HT[m] . aW[:,c] + ab[c], blocks 0..126 ----
    if (b < 127) {
        const float* h = HT + (size_t)b * EN;
        unsigned long long hv = AL64(h + tid * 2);
        float h0 = af((unsigned)hv), h1 = af((unsigned)(hv >> 32));
        f32x4 w4 = *(const f32x4*)(aW + (size_t)tid * 4);   // {W[2t][0],W[2t][1],W[2t+1][0],W[2t+1][1]}
        float s0 = h0 * w4.x + h1 * w4.z;
        float s1 = h0 * w4.y + h1 * w4.w;
#pragma unroll
        for (int off = 32; off; off >>= 1) { s0 += __shfl_down(s0, off, 64); s1 += __shfl_down(s1, off, 64); }
        if (lane == 0) { lred[wv][0] = s0; lred[wv][1] = s1; }
        __syncthreads();
        if (tid == 0) {
            float t0 = ab[0], t1 = ab[1];
#pragma unroll
            for (int q = 0; q < 16; ++q) { t0 += lred[q][0]; t1 += lred[q][1]; }
            out[64 * EN + b * 2]     = t0;
            out[64 * EN + b * 2 + 1] = t1;
        }
    }
}

extern "C" void kernel_launch(void* const* d_in, const int* in_sizes, int n_in,
                              void* d_out, int out_size, void* d_ws, size_t ws_size,
                              hipStream_t stream)
{
    const float* x0   = (const float*)d_in[0];
    // d_in[1] = fixed_actions (constant 63 reduces + 64 shifts) — structure hardcoded
    const float* arW  = (const float*)d_in[2];
    const float* arb  = (const float*)d_in[3];
    const float* aW   = (const float*)d_in[4];
    const float* ab   = (const float*)d_in[5];
    const float* ul1W = (const float*)d_in[6];
    const float* ul1b = (const float*)d_in[7];
    const float* ul2W = (const float*)d_in[8];
    const float* ul2b = (const float*)d_in[9];
    const float* ur1W = (const float*)d_in[10];
    const float* ur1b = (const float*)d_in[11];
    const float* ur2W = (const float*)d_in[12];
    const float* ur2b = (const float*)d_in[13];

    float* ws  = (float*)d_ws;
    float* out = (float*)d_out;
    float* T   = ws + T_OFF;
    float* Hb  = ws + H_OFF;
    float* RT1 = ws + H_OFF;    // H region dead after chain; reused for RT1
    float* HT  = ws + HT_OFF;
    float* P   = ws + P_OFF;
    unsigned* FLG = (unsigned*)(ws + FLG_OFF);

    // one memset: T+H sentinels and flag region (0xFFFFFFFF != 1)
    hipMemsetAsync(ws, 0xFF, (size_t)(129 * EN) * sizeof(float), stream);

    void* args[] = { (void*)&x0, (void*)&ul1W, (void*)&ul1b, (void*)&ul2W, (void*)&ul2b,
                     (void*)&ur1W, (void*)&ur1b, (void*)&ur2W, (void*)&ur2b,
                     (void*)&arW, (void*)&arb, (void*)&aW, (void*)&ab,
                     (void*)&T, (void*)&Hb, (void*)&RT1, (void*)&HT, (void*)&P,
                     (void*)&FLG, (void*)&out };
    hipError_t err = hipLaunchCooperativeKernel(reinterpret_cast<void*>(mega_kernel),
                                                dim3(NCH), dim3(CTH), args, 0, stream);
    if (err != hipSuccess) {
        (void)hipGetLastError();
        // 256 blocks x 1024 threads = exactly 1 block/CU -> co-resident
        mega_kernel<<<dim3(NCH), dim3(CTH), 0, stream>>>(
            x0, ul1W, ul1b, ul2W, ul2b, ur1W, ur1b, ur2W, ur2b,
            arW, arb, aW, ab, T, Hb, RT1, HT, P, FLG, out);
    }
}